// Round 9
// baseline (490.093 us; speedup 1.0000x reference)
//
#include <hip/hip_runtime.h>

// ---------------------------------------------------------------------------
// GNN forward, MI355X. All I/O f32; split-f16 MFMA for the edge MLP (bit-
// identical to R8's verified mm2/mm3); Q/P/GRU/readout in f32 VALU.
// R9: two-kernel iteration, shaped by the occupancy law fitted over R4-R8
// (effective schedulable LDS ~128KiB/CU; VGPR bucket 16 waves/CU at <=128
// total). k_edge: 24KB LDS, (256,4) -> 4 blocks/CU = 50% occupancy; Q,P from
// global (computed once/iter, kills the 8x per-batch P recomputation);
// in-wave shfl butterfly segment-sum. k_node: GRU + node + fused next-iter
// Q/P projection (or readout). k_pre seeds iter-1 Q/P after fc1a.
// ws: H 2MB | MI 1MB | Q 2MB | P 2MB | weights ~131KB  (~7.2MB total).
// ---------------------------------------------------------------------------

typedef _Float16 f16;
typedef _Float16 h8 __attribute__((ext_vector_type(8)));
typedef float f4 __attribute__((ext_vector_type(4)));

#define MFMA16(a, b, c) __builtin_amdgcn_mfma_f32_16x16x32_f16(a, b, c, 0, 0, 0)
#define WFENCE()                        \
  do {                                  \
    __builtin_amdgcn_wave_barrier();    \
    __asm__ volatile("" ::: "memory");  \
  } while (0)

// ---- workspace byte offsets ----
#define H_OFF 0           // f32 [128][64][64]
#define MI_OFF 2097152    // f32 [128][64][32]
#define Q_OFF 3145728     // f32 [128][64][64]  (b2a folded)
#define P_OFF 5242880     // f32 [128][64][64]
#define WQ_OFF 7340032
// within WQ:
#define O_W45B 0         // f32 w64[64], w65[64], b2a[64]
#define O_W2BTH 768      // f16 [32v][64k] hi of W2b[k][v]
#define O_W2BTL 4864     // f16 lo
#define O_B2B 8960       // f32 [32]
#define O_W2CTH 9088     // f16 [32v][32k] hi
#define O_W2CTL 11136    // f16 lo
#define O_B2C 13184      // f32 [32]
#define O_WXT 13312      // f32 [192u][32k] = Wx[k][u]
#define O_UXT 37888      // f32 [192u][64k] = Ux[k][u]
#define O_BX 87040       // f32 [192]
#define O_BH 87808       // f32 [192]
#define O_W3BT 88576     // f32 [32f][64k] = W3b[k][f]
#define O_B3B 96768      // f32 [32]
#define O_W4AT 96896     // f32 [64u][32k] = W4a[k][u]
#define O_B4A 105088     // f32 [64]
#define O_W4BT 105344    // f32 [32v][64k] = W4b[k][v]
#define O_B4B 113536     // f32 [32]
#define O_W4CT 113664    // f32 [32f][32k] = W4c[k][f]
#define O_B4C 117760     // f32 [32]
#define O_W2ALOT 117888  // f32 [64u][32k] = W2a[k][u], k<32
#define O_W2AHIT 126080  // f32 [64u][32k] = W2a[32+k][u]

// ---- k_edge LDS (24576 B total) ----
#define LE_M2W 0      // per-wave m2: 4 x 2560 (hi 1280 | lo 1280)
#define LE_W2BH 10240 // f16 [32v][72] (row-padded 64->72)
#define LE_W2BL 14848
#define LE_W2CH 19456 // f16 [32v][40] (row-padded 32->40)
#define LE_W2CL 22016
#define LE_TOTAL 24576

// ---- k_node LDS ----
#define LN_H32 0      // f32 [16][64]
#define LN_R 4096
#define LN_Z 8192
#define LN_XN 12288
#define LN_HNG 16384
#define LN_HN32 20480
#define LN_ND 24576   // f32 [16][32]
#define LN_T1 26624   // f32 [16][68]
#define LN_T2 30976   // f32 [16][36]
#define LN_TOTAL 33280

__device__ __forceinline__ float fast_rcp(float x) {
#if __has_builtin(__builtin_amdgcn_rcpf)
  return __builtin_amdgcn_rcpf(x);
#else
  return 1.0f / x;
#endif
}
// jax.nn.gelu(approximate=True) — R5-exact formulation (absmax-16-verified)
__device__ __forceinline__ float gelu_f(float x) {
  float x3 = x * x * x;
  float u = -1.5957691216057308f * fmaf(0.044715f, x3, x);
  return x * fast_rcp(1.f + __expf(u));
}
__device__ __forceinline__ float sigm_f(float x) {
  return fast_rcp(1.f + __expf(-x));
}
__device__ __forceinline__ void splitw(float v, f16& h, f16& l) {
  h = (f16)v;
  l = (f16)(v - (float)h);
}

// ===========================================================================
__global__ __launch_bounds__(256) void k_pre(
    const float* __restrict__ node0, const float* __restrict__ W1,
    const float* __restrict__ b1, const float* __restrict__ W2a,
    const float* __restrict__ b2a, const float* __restrict__ W2b,
    const float* __restrict__ b2b, const float* __restrict__ W2c,
    const float* __restrict__ b2c, const float* __restrict__ Wx,
    const float* __restrict__ Ux, const float* __restrict__ bx,
    const float* __restrict__ bh, const float* __restrict__ W3b,
    const float* __restrict__ b3b, const float* __restrict__ W4a,
    const float* __restrict__ b4a, const float* __restrict__ W4b,
    const float* __restrict__ b4b, const float* __restrict__ W4c,
    const float* __restrict__ b4c, float* __restrict__ ws) {
  const int t = threadIdx.x;
  const int blk = blockIdx.x;
  char* wsb = (char*)ws;
  float* Qbuf = (float*)(wsb + Q_OFF);
  float* Pbuf = (float*)(wsb + P_OFF);
  char* W = wsb + WQ_OFF;

  if (blk < 256) {  // fc1a + iter-1 Q/P projection: 2 blocks/batch, 32 nodes
    __shared__ float sNode[1024];
    const int b = blk >> 1;
    const int n0 = (blk & 1) << 5;
    for (int idx = t; idx < 1024; idx += 256) {
      const int n = idx >> 5, f = idx & 31;
      float acc = b1[f];
#pragma unroll
      for (int k = 0; k < 8; ++k)
        acc = fmaf(node0[((size_t)(b * 64 + n0 + n)) * 8 + k], W1[k * 32 + f], acc);
      sNode[idx] = acc;
    }
    __syncthreads();
    for (int o = t; o < 4096; o += 256) {
      const int n = o >> 7;
      const int r = o & 127;
      const int u = r >> 1;
      const int isP = r & 1;
      const float* nr = sNode + n * 32;
      const float* wc = W2a + (isP ? 32 * 64 : 0) + u;
      float acc = isP ? 0.f : b2a[u];
#pragma unroll 8
      for (int k = 0; k < 32; ++k) acc = fmaf(nr[k], wc[k * 64], acc);
      const size_t gn = (size_t)(b * 64 + n0 + n);
      if (isP)
        Pbuf[gn * 64 + u] = acc;
      else
        Qbuf[gn * 64 + u] = acc;
    }
  } else if (blk == 256) {
    float* wb = (float*)(W + O_W45B);
    if (t < 64) {
      wb[t] = W2a[64 * 64 + t];
      wb[64 + t] = W2a[65 * 64 + t];
      wb[128 + t] = b2a[t];
    }
    f16* bth = (f16*)(W + O_W2BTH);
    f16* btl = (f16*)(W + O_W2BTL);
    for (int idx = t; idx < 2048; idx += 256) {
      const int k = idx >> 5, v = idx & 31;
      f16 h_, l_;
      splitw(W2b[k * 32 + v], h_, l_);
      bth[v * 64 + k] = h_;
      btl[v * 64 + k] = l_;
    }
    float* b2bf = (float*)(W + O_B2B);
    if (t < 32) b2bf[t] = b2b[t];
    f16* cth = (f16*)(W + O_W2CTH);
    f16* ctl = (f16*)(W + O_W2CTL);
    for (int idx = t; idx < 1024; idx += 256) {
      const int k = idx >> 5, v = idx & 31;
      f16 h_, l_;
      splitw(W2c[k * 32 + v], h_, l_);
      cth[v * 32 + k] = h_;
      ctl[v * 32 + k] = l_;
    }
    float* b2cf = (float*)(W + O_B2C);
    if (t < 32) b2cf[t] = b2c[t];
    float* lot = (float*)(W + O_W2ALOT);
    float* hit = (float*)(W + O_W2AHIT);
    for (int idx = t; idx < 2048; idx += 256) {
      const int k = idx >> 6, u = idx & 63;
      lot[u * 32 + k] = W2a[k * 64 + u];
      hit[u * 32 + k] = W2a[(k + 32) * 64 + u];
    }
  } else if (blk == 257) {
    float* wxt = (float*)(W + O_WXT);
    for (int idx = t; idx < 6144; idx += 256) {
      const int u = idx >> 5, k = idx & 31;
      wxt[u * 32 + k] = Wx[k * 192 + u];
    }
    float* bxf = (float*)(W + O_BX);
    float* bhf = (float*)(W + O_BH);
    if (t < 192) {
      bxf[t] = bx[t];
      bhf[t] = bh[t];
    }
  } else if (blk == 258) {
    float* uxt = (float*)(W + O_UXT);
    for (int idx = t; idx < 12288; idx += 256) {
      const int u = idx >> 6, k = idx & 63;
      uxt[u * 64 + k] = Ux[k * 192 + u];
    }
  } else {
    float* w3bt = (float*)(W + O_W3BT);
    for (int idx = t; idx < 2048; idx += 256) {
      const int f = idx >> 6, k = idx & 63;
      w3bt[f * 64 + k] = W3b[k * 32 + f];
    }
    float* b3bf = (float*)(W + O_B3B);
    if (t < 32) b3bf[t] = b3b[t];
    float* w4at = (float*)(W + O_W4AT);
    for (int idx = t; idx < 2048; idx += 256) {
      const int u = idx >> 5, k = idx & 31;
      w4at[u * 32 + k] = W4a[k * 64 + u];
    }
    float* b4af = (float*)(W + O_B4A);
    if (t < 64) b4af[t] = b4a[t];
    float* w4bt = (float*)(W + O_W4BT);
    for (int idx = t; idx < 2048; idx += 256) {
      const int v = idx >> 6, k = idx & 63;
      w4bt[v * 64 + k] = W4b[k * 32 + v];
    }
    float* b4bf = (float*)(W + O_B4B);
    if (t < 32) b4bf[t] = b4b[t];
    float* w4ct = (float*)(W + O_W4CT);
    for (int idx = t; idx < 1024; idx += 256) {
      const int f = idx >> 5, k = idx & 31;
      w4ct[f * 32 + k] = W4c[k * 32 + f];
    }
    float* b4cf = (float*)(W + O_B4C);
    if (t < 32) b4cf[t] = b4c[t];
  }
}

// ===========================================================================
// Edge MLP: block = (batch, 8 source nodes), wave owns 2 nodes' edge sets.
__global__ __launch_bounds__(256, 4) void k_edge(
    const float* __restrict__ edge, float* __restrict__ ws) {
  __shared__ alignas(16) char sm[LE_TOTAL];
  f16* sW2BH = (f16*)(sm + LE_W2BH);
  f16* sW2BL = (f16*)(sm + LE_W2BL);
  f16* sW2CH = (f16*)(sm + LE_W2CH);
  f16* sW2CL = (f16*)(sm + LE_W2CL);

  const int tid = threadIdx.x;
  const int lane = tid & 63;
  const int wave = tid >> 6;
  const int col = lane & 15;
  const int quad = lane >> 4;
  const int b = blockIdx.x >> 3;
  const int i0 = (blockIdx.x & 7) << 3;

  char* wsb = (char*)ws;
  float* MI = (float*)(wsb + MI_OFF);
  const float* Qbuf = (const float*)(wsb + Q_OFF);
  const float* Pbuf = (const float*)(wsb + P_OFF);
  const char* W = wsb + WQ_OFF;
  const float* w45b = (const float*)(W + O_W45B);
  const f16* W2BTHg = (const f16*)(W + O_W2BTH);
  const f16* W2BTLg = (const f16*)(W + O_W2BTL);
  const float* b2b_g = (const float*)(W + O_B2B);
  const f16* W2CTHg = (const f16*)(W + O_W2CTH);
  const f16* W2CTLg = (const f16*)(W + O_W2CTL);
  const float* b2c_g = (const float*)(W + O_B2C);

  // stage W2b/W2c hi/lo into padded LDS (bit-identical fragments to R8)
  for (int idx = tid; idx < 1024; idx += 256) {
    const int v = idx >> 5, k2 = idx & 31;
    ((unsigned int*)sW2BH)[v * 36 + k2] = ((const unsigned int*)W2BTHg)[idx];
    ((unsigned int*)sW2BL)[v * 36 + k2] = ((const unsigned int*)W2BTLg)[idx];
  }
  for (int idx = tid; idx < 512; idx += 256) {
    const int v = idx >> 4, k2 = idx & 15;
    ((unsigned int*)sW2CH)[v * 20 + k2] = ((const unsigned int*)W2CTHg)[idx];
    ((unsigned int*)sW2CL)[v * 20 + k2] = ((const unsigned int*)W2CTLg)[idx];
  }
  __syncthreads();

  const float bb2[2] = {b2b_g[col], b2b_g[16 + col]};
  const float bc2[2] = {b2c_g[col], b2c_g[16 + col]};
  f4 wav[2][2], wbv[2][2];
#pragma unroll
  for (int kh = 0; kh < 2; ++kh) {
#pragma unroll
    for (int p = 0; p < 2; ++p) {
      wav[kh][p] = *(const f4*)(w45b + kh * 32 + quad * 8 + p * 4);
      wbv[kh][p] = *(const f4*)(w45b + 64 + kh * 32 + quad * 8 + p * 4);
    }
  }
  f16* m2h = (f16*)(sm + LE_M2W + wave * 2560);
  f16* m2l = m2h + 640;

#pragma unroll 1
  for (int cc2 = 0; cc2 < 2; ++cc2) {
    const int c = wave + 4 * cc2;
    const int ig = i0 + c;
    // Q row (b2a folded), broadcast across cols: hoist to registers
    f4 qb[2][2];
#pragma unroll
    for (int kh = 0; kh < 2; ++kh)
#pragma unroll
      for (int p = 0; p < 2; ++p)
        qb[kh][p] = *(const f4*)(Qbuf + ((size_t)(b * 64 + ig)) * 64 + kh * 32 +
                                 quad * 8 + p * 4);
    const float* erow = edge + ((size_t)b * 4032 + (size_t)ig * 63) * 2;
    float ev0[4], ev1[4];
#pragma unroll
    for (int mt = 0; mt < 4; ++mt) {
      const int ko = mt * 16 + col;
      if (ko < 63) {
        const float2 e = *(const float2*)(erow + ko * 2);
        ev0[mt] = e.x;
        ev1[mt] = e.y;
      } else {
        ev0[mt] = 0.f;
        ev1[mt] = 0.f;
      }
    }
    float racc[2] = {0.f, 0.f};
#pragma unroll
    for (int mt = 0; mt < 4; ++mt) {
      const int ko = mt * 16 + col;
      int j = ko + ((ko >= ig) ? 1 : 0);
      j = (j > 63) ? 63 : j;
      const float e0 = ev0[mt], e1 = ev1[mt];
      // m1 A-fragments straight into registers (P rows from global/L2)
      h8 ah[2], al[2];
#pragma unroll
      for (int kh = 0; kh < 2; ++kh) {
        const float* prow =
            Pbuf + ((size_t)(b * 64 + j)) * 64 + kh * 32 + quad * 8;
        const f4 p0 = *(const f4*)prow;
        const f4 p1 = *(const f4*)(prow + 4);
#pragma unroll
        for (int jj = 0; jj < 4; ++jj) {
          float v = qb[kh][0][jj] + p0[jj];
          v = fmaf(e1, wbv[kh][0][jj], fmaf(e0, wav[kh][0][jj], v));
          float g = gelu_f(v) * 0.015625f;
          f16 hi = (f16)g;
          ah[kh][jj] = hi;
          al[kh][jj] = (f16)(g - (float)hi);
          v = qb[kh][1][jj] + p1[jj];
          v = fmaf(e1, wbv[kh][1][jj], fmaf(e0, wav[kh][1][jj], v));
          g = gelu_f(v) * 0.015625f;
          hi = (f16)g;
          ah[kh][4 + jj] = hi;
          al[kh][4 + jj] = (f16)(g - (float)hi);
        }
      }
      // mm2 (3-term split, K=64) — R8-exact order, B from LDS
#pragma unroll
      for (int nt = 0; nt < 2; ++nt) {
        const f16* rbh = sW2BH + (nt * 16 + col) * 72 + quad * 8;
        const f16* rbl = sW2BL + (nt * 16 + col) * 72 + quad * 8;
        const h8 bh0 = *(const h8*)rbh;
        const h8 bh1 = *(const h8*)(rbh + 32);
        const h8 bl0 = *(const h8*)rbl;
        const h8 bl1 = *(const h8*)(rbl + 32);
        f4 cm = {0.f, 0.f, 0.f, 0.f};
        cm = MFMA16(ah[0], bh0, cm);
        cm = MFMA16(ah[1], bh1, cm);
        cm = MFMA16(ah[0], bl0, cm);
        cm = MFMA16(ah[1], bl1, cm);
        cm = MFMA16(al[0], bh0, cm);
        cm = MFMA16(al[1], bh1, cm);
#pragma unroll
        for (int r = 0; r < 4; ++r) {
          const float g = gelu_f(fmaf(64.f, cm[r], bb2[nt])) * 0.015625f;
          const f16 hi = (f16)g;
          const int o = (quad * 4 + r) * 40 + nt * 16 + col;
          m2h[o] = hi;
          m2l[o] = (f16)(g - (float)hi);
        }
      }
      WFENCE();  // C-layout writes before A-layout reads (same wave)
      const h8 a2h = *(const h8*)(m2h + col * 40 + quad * 8);
      const h8 a2l = *(const h8*)(m2l + col * 40 + quad * 8);
      WFENCE();  // reads before next mt's writes (WAR)
      // mm3 (3-term split, K=32) + masked register segment-sum
#pragma unroll
      for (int nt = 0; nt < 2; ++nt) {
        const h8 bch = *(const h8*)(sW2CH + (nt * 16 + col) * 40 + quad * 8);
        const h8 bcl = *(const h8*)(sW2CL + (nt * 16 + col) * 40 + quad * 8);
        f4 dm = {0.f, 0.f, 0.f, 0.f};
        dm = MFMA16(a2h, bch, dm);
        dm = MFMA16(a2h, bcl, dm);
        dm = MFMA16(a2l, bch, dm);
#pragma unroll
        for (int r = 0; r < 4; ++r) {
          const int slot3 = mt * 16 + quad * 4 + r;
          const float g = gelu_f(fmaf(64.f, dm[r], bc2[nt]));
          racc[nt] += (slot3 != 63) ? g : 0.f;
        }
      }
    }
    // cross-quad reduction in-wave (lanes with same col), then store m_i
    racc[0] += __shfl_xor(racc[0], 16);
    racc[0] += __shfl_xor(racc[0], 32);
    racc[1] += __shfl_xor(racc[1], 16);
    racc[1] += __shfl_xor(racc[1], 32);
    if (lane < 32)
      MI[((size_t)(b * 64 + ig)) * 32 + lane] = (lane < 16) ? racc[0] : racc[1];
  }
}

// ===========================================================================
// GRU + node update + (next-iter Q/P projection | readout). 512 blocks.
__global__ __launch_bounds__(256) void k_node(
    float* __restrict__ ws, const float* __restrict__ h_in,
    float* __restrict__ out, const int is_last) {
  __shared__ alignas(16) char sm[LN_TOTAL];
  float* sH32 = (float*)(sm + LN_H32);
  float* sR = (float*)(sm + LN_R);
  float* sZ = (float*)(sm + LN_Z);
  float* sXn = (float*)(sm + LN_XN);
  float* sHng = (float*)(sm + LN_HNG);
  float* sHn32 = (float*)(sm + LN_HN32);
  float* sNd = (float*)(sm + LN_ND);
  float* sT1 = (float*)(sm + LN_T1);
  float* sT2 = (float*)(sm + LN_T2);

  const int tid = threadIdx.x;
  const int lane = tid & 63;
  const int wave = tid >> 6;
  const int b = blockIdx.x >> 2;
  const int i0 = (blockIdx.x & 3) << 4;

  char* wsb = (char*)ws;
  float* h_ws = (float*)(wsb + H_OFF);
  const float* MI = (const float*)(wsb + MI_OFF);
  float* Qbuf = (float*)(wsb + Q_OFF);
  float* Pbuf = (float*)(wsb + P_OFF);
  const char* W = wsb + WQ_OFF;
  const float* w45b = (const float*)(W + O_W45B);
  const float* WxT = (const float*)(W + O_WXT);
  const float* UxT = (const float*)(W + O_UXT);
  const float* bx_g = (const float*)(W + O_BX);
  const float* bh_g = (const float*)(W + O_BH);
  const float* W3bT = (const float*)(W + O_W3BT);
  const float* b3b_g = (const float*)(W + O_B3B);
  const float* W4aT = (const float*)(W + O_W4AT);
  const float* b4a_g = (const float*)(W + O_B4A);
  const float* W4bT = (const float*)(W + O_W4BT);
  const float* b4b_g = (const float*)(W + O_B4B);
  const float* W4cT = (const float*)(W + O_W4CT);
  const float* b4c_g = (const float*)(W + O_B4C);
  const float* W2aLOT = (const float*)(W + O_W2ALOT);
  const float* W2aHIT = (const float*)(W + O_W2AHIT);

  {
    const int nl = tid >> 4;
    const int k4 = (tid & 15) * 4;
    *(float4*)(sH32 + tid * 4) =
        *(const float4*)(h_in + ((size_t)(b * 64 + i0 + nl)) * 64 + k4);
  }
  __syncthreads();

  // GRU gates (R5-verified structure; m_i from global MI)
  {
    const int n = tid >> 4;
    const int u0 = tid & 15;
    float4 mi4[8], hh4[16];
    const float4* mrow = (const float4*)(MI + ((size_t)(b * 64 + i0 + n)) * 32);
#pragma unroll
    for (int i = 0; i < 8; ++i) mi4[i] = mrow[i];
    const float4* hrow = (const float4*)(sH32 + n * 64);
#pragma unroll
    for (int i = 0; i < 16; ++i) hh4[i] = hrow[i];
#pragma unroll
    for (int gi = 0; gi < 12; ++gi) {
      const int u = u0 + 16 * gi;
      const float4* wx = (const float4*)(WxT + u * 32);
      float ax = 0.f;
#pragma unroll
      for (int i = 0; i < 8; ++i) {
        const float4 w = wx[i];
        ax = fmaf(mi4[i].x, w.x, ax);
        ax = fmaf(mi4[i].y, w.y, ax);
        ax = fmaf(mi4[i].z, w.z, ax);
        ax = fmaf(mi4[i].w, w.w, ax);
      }
      const float4* ux = (const float4*)(UxT + u * 64);
      float ah_ = 0.f;
#pragma unroll
      for (int i = 0; i < 16; ++i) {
        const float4 w = ux[i];
        ah_ = fmaf(hh4[i].x, w.x, ah_);
        ah_ = fmaf(hh4[i].y, w.y, ah_);
        ah_ = fmaf(hh4[i].z, w.z, ah_);
        ah_ = fmaf(hh4[i].w, w.w, ah_);
      }
      const float bxv = bx_g[u], bhv = bh_g[u];
      if (u < 64) {
        sR[n * 64 + u] = sigm_f(ax + ah_ + bxv + bhv);
      } else if (u < 128) {
        sZ[n * 64 + u - 64] = sigm_f(ax + ah_ + bxv + bhv);
      } else {
        sXn[n * 64 + u - 128] = ax + bxv;
        sHng[n * 64 + u - 128] = ah_ + bhv;
      }
    }
  }
  __syncthreads();

#pragma unroll
  for (int p = 0; p < 4; ++p) {
    const int nl = wave + 4 * p;
    const int u = lane;
    const float r_ = sR[nl * 64 + u];
    const float z_ = sZ[nl * 64 + u];
    const float n_ = gelu_f(fmaf(r_, sHng[nl * 64 + u], sXn[nl * 64 + u]));
    const float hold = sH32[nl * 64 + u];
    const float hnew = (1.f - z_) * n_ + z_ * hold;
    sHn32[nl * 64 + u] = hnew;
    h_ws[((size_t)(b * 64 + i0 + nl)) * 64 + u] = hnew;
  }
  __syncthreads();

  // node = h_new @ W3b + b3b -> sNd
  for (int t = tid; t < 512; t += 256) {
    const int n = t >> 5, f = t & 31;
    float acc = b3b_g[f];
    const float4* hr = (const float4*)(sHn32 + n * 64);
    const float4* wr = (const float4*)(W3bT + f * 64);
#pragma unroll
    for (int i = 0; i < 16; ++i) {
      const float4 hv = hr[i];
      const float4 wv = wr[i];
      acc = fmaf(hv.x, wv.x, acc);
      acc = fmaf(hv.y, wv.y, acc);
      acc = fmaf(hv.z, wv.z, acc);
      acc = fmaf(hv.w, wv.w, acc);
    }
    sNd[n * 32 + f] = acc;
  }
  __syncthreads();

  if (!is_last) {
    // next-iteration Q (b2a folded) and P projections, f32 VALU
    const int n = tid >> 4;
    const int uu = tid & 15;
    const float4* nr = (const float4*)(sNd + n * 32);
    float4 nv[8];
#pragma unroll
    for (int i = 0; i < 8; ++i) nv[i] = nr[i];
    const size_t gn = (size_t)(b * 64 + i0 + n);
#pragma unroll
    for (int k8 = 0; k8 < 4; ++k8) {
      const int u = uu + (k8 << 4);
      const float4* wq = (const float4*)(W2aLOT + u * 32);
      const float4* wp = (const float4*)(W2aHIT + u * 32);
      float qa = w45b[128 + u];
      float pa = 0.f;
#pragma unroll
      for (int i = 0; i < 8; ++i) {
        const float4 a = nv[i];
        const float4 q = wq[i];
        const float4 p = wp[i];
        qa = fmaf(a.x, q.x, qa);
        qa = fmaf(a.y, q.y, qa);
        qa = fmaf(a.z, q.z, qa);
        qa = fmaf(a.w, q.w, qa);
        pa = fmaf(a.x, p.x, pa);
        pa = fmaf(a.y, p.y, pa);
        pa = fmaf(a.z, p.z, pa);
        pa = fmaf(a.w, p.w, pa);
      }
      Qbuf[gn * 64 + u] = qa;
      Pbuf[gn * 64 + u] = pa;
    }
  } else {
    for (int t = tid; t < 1024; t += 256) {
      const int n = t >> 6, u = t & 63;
      float acc = b4a_g[u];
      const float4* ar = (const float4*)(sNd + n * 32);
      const float4* wr = (const float4*)(W4aT + u * 32);
#pragma unroll
      for (int i = 0; i < 8; ++i) {
        const float4 av = ar[i];
        const float4 wv = wr[i];
        acc = fmaf(av.x, wv.x, acc);
        acc = fmaf(av.y, wv.y, acc);
        acc = fmaf(av.z, wv.z, acc);
        acc = fmaf(av.w, wv.w, acc);
      }
      sT1[n * 68 + u] = acc;
    }
    __syncthreads();
    for (int t = tid; t < 512; t += 256) {
      const int n = t >> 5, v = t & 31;
      float acc = b4b_g[v];
      const float4* ar = (const float4*)(sT1 + n * 68);
      const float4* wr = (const float4*)(W4bT + v * 64);
#pragma unroll
      for (int i = 0; i < 16; ++i) {
        const float4 av = ar[i];
        const float4 wv = wr[i];
        acc = fmaf(av.x, wv.x, acc);
        acc = fmaf(av.y, wv.y, acc);
        acc = fmaf(av.z, wv.z, acc);
        acc = fmaf(av.w, wv.w, acc);
      }
      sT2[n * 36 + v] = acc;
    }
    __syncthreads();
    for (int t = tid; t < 512; t += 256) {
      const int n = t >> 5, f = t & 31;
      float acc = b4c_g[f];
      const float4* ar = (const float4*)(sT2 + n * 36);
      const float4* wr = (const float4*)(W4cT + f * 32);
#pragma unroll
      for (int i = 0; i < 8; ++i) {
        const float4 av = ar[i];
        const float4 wv = wr[i];
        acc = fmaf(av.x, wv.x, acc);
        acc = fmaf(av.y, wv.y, acc);
        acc = fmaf(av.z, wv.z, acc);
        acc = fmaf(av.w, wv.w, acc);
      }
      out[((size_t)(b * 64 + i0 + n)) * 32 + f] = acc;
    }
  }
}

// ===========================================================================
extern "C" void kernel_launch(void* const* d_in, const int* in_sizes, int n_in,
                              void* d_out, int out_size, void* d_ws, size_t ws_size,
                              hipStream_t stream) {
  (void)in_sizes;
  (void)n_in;
  (void)out_size;
  (void)ws_size;
  const float* node0 = (const float*)d_in[0];
  const float* edge = (const float*)d_in[1];
  const float* hin = (const float*)d_in[4];
  const float* W1 = (const float*)d_in[5];
  const float* b1 = (const float*)d_in[6];
  const float* W2a = (const float*)d_in[7];
  const float* b2a = (const float*)d_in[8];
  const float* W2b = (const float*)d_in[9];
  const float* b2b = (const float*)d_in[10];
  const float* W2c = (const float*)d_in[11];
  const float* b2c = (const float*)d_in[12];
  const float* Wx = (const float*)d_in[13];
  const float* Ux = (const float*)d_in[14];
  const float* bx = (const float*)d_in[15];
  const float* bh = (const float*)d_in[16];
  const float* W3b = (const float*)d_in[17];
  const float* b3b = (const float*)d_in[18];
  const float* W4a = (const float*)d_in[19];
  const float* b4a = (const float*)d_in[20];
  const float* W4b = (const float*)d_in[21];
  const float* b4b = (const float*)d_in[22];
  const float* W4c = (const float*)d_in[23];
  const float* b4c = (const float*)d_in[24];

  float* ws = (float*)d_ws;
  char* wsb = (char*)d_ws;
  float* h_ws = (float*)(wsb + H_OFF);
  float* out = (float*)d_out;

  k_pre<<<dim3(260), dim3(256), 0, stream>>>(node0, W1, b1, W2a, b2a, W2b, b2b, W2c,
                                             b2c, Wx, Ux, bx, bh, W3b, b3b, W4a, b4a,
                                             W4b, b4b, W4c, b4c, ws);
  k_edge<<<dim3(1024), dim3(256), 0, stream>>>(edge, ws);
  k_node<<<dim3(512), dim3(256), 0, stream>>>(ws, hin, nullptr, 0);
  k_edge<<<dim3(1024), dim3(256), 0, stream>>>(edge, ws);
  k_node<<<dim3(512), dim3(256), 0, stream>>>(ws, h_ws, nullptr, 0);
  k_edge<<<dim3(1024), dim3(256), 0, stream>>>(edge, ws);
  k_node<<<dim3(512), dim3(256), 0, stream>>>(ws, h_ws, out, 1);
}

// Round 10
// 302.898 us; speedup vs baseline: 1.6180x; 1.6180x over previous
//
#include <hip/hip_runtime.h>

// ---------------------------------------------------------------------------
// GNN forward, MI355X. All I/O f32; split-f16 MFMA for the edge MLP (bit-
// identical to R8's verified mm2/mm3); Q/P/GRU/readout in f32 VALU.
// R10: k_node fix. R9 counters: k_node = 88us x3 with VALUBusy 6.5%, MFMA 0,
// HBM 1.2% -> pure latency on 16-lane-scattered global reads of Wx/Ux rows
// (every float4 touches 16 cache lines; ~288/thread; 8 waves/CU can't hide).
// Now: gates computed in three 64-col passes with Ux/Wx thirds staged to
// padded LDS (coalesced stage, <=2-way-bank compute reads); MI staged; Q/P
// projection tail reads W2a from padded LDS. Per-thread FMA order unchanged
// -> bit-identical results. k_pre/k_edge unchanged from R9.
// ---------------------------------------------------------------------------

typedef _Float16 f16;
typedef _Float16 h8 __attribute__((ext_vector_type(8)));
typedef float f4 __attribute__((ext_vector_type(4)));

#define MFMA16(a, b, c) __builtin_amdgcn_mfma_f32_16x16x32_f16(a, b, c, 0, 0, 0)
#define WFENCE()                        \
  do {                                  \
    __builtin_amdgcn_wave_barrier();    \
    __asm__ volatile("" ::: "memory");  \
  } while (0)

// ---- workspace byte offsets ----
#define H_OFF 0           // f32 [128][64][64]
#define MI_OFF 2097152    // f32 [128][64][32]
#define Q_OFF 3145728     // f32 [128][64][64]  (b2a folded)
#define P_OFF 5242880     // f32 [128][64][64]
#define WQ_OFF 7340032
// within WQ:
#define O_W45B 0         // f32 w64[64], w65[64], b2a[64]
#define O_W2BTH 768      // f16 [32v][64k] hi of W2b[k][v]
#define O_W2BTL 4864     // f16 lo
#define O_B2B 8960       // f32 [32]
#define O_W2CTH 9088     // f16 [32v][32k] hi
#define O_W2CTL 11136    // f16 lo
#define O_B2C 13184      // f32 [32]
#define O_WXT 13312      // f32 [192u][32k] = Wx[k][u]
#define O_UXT 37888      // f32 [192u][64k] = Ux[k][u]
#define O_BX 87040       // f32 [192]
#define O_BH 87808       // f32 [192]
#define O_W3BT 88576     // f32 [32f][64k] = W3b[k][f]
#define O_B3B 96768      // f32 [32]
#define O_W4AT 96896     // f32 [64u][32k] = W4a[k][u]
#define O_B4A 105088     // f32 [64]
#define O_W4BT 105344    // f32 [32v][64k] = W4b[k][v]
#define O_B4B 113536     // f32 [32]
#define O_W4CT 113664    // f32 [32f][32k] = W4c[k][f]
#define O_B4C 117760     // f32 [32]
#define O_W2ALOT 117888  // f32 [64u][32k] = W2a[k][u], k<32
#define O_W2AHIT 126080  // f32 [64u][32k] = W2a[32+k][u]

// ---- k_edge LDS (24576 B total) ----
#define LE_M2W 0      // per-wave m2: 4 x 2560 (hi 1280 | lo 1280)
#define LE_W2BH 10240 // f16 [32v][72] (row-padded 64->72)
#define LE_W2BL 14848
#define LE_W2CH 19456 // f16 [32v][40] (row-padded 32->40)
#define LE_W2CL 22016
#define LE_TOTAL 24576

// ---- k_node LDS (55296 B total) ----
#define LN_H32 0      // f32 [16][64]
#define LN_MI 4096    // f32 [16][32]
#define LN_ND 6144    // f32 [16][32]
#define LN_WS 8192    // stage region (26624 B):
                      //   gates: sUx f32 [64][68] @8192, sWx f32 [64][36] @25600
                      //   !last: sQW f32 [64][36] @8192, sPW f32 [64][36] @17408
                      //   last:  T1 f32 [16][68] @8192, T2 f32 [16][36] @12544
#define LN_UX 8192
#define LN_WX 25600
#define LN_QW 8192
#define LN_PW 17408
#define LN_T1 8192
#define LN_T2 12544
#define LN_R 34816
#define LN_Z 38912
#define LN_XN 43008
#define LN_HNG 47104
#define LN_HN32 51200
#define LN_TOTAL 55296

__device__ __forceinline__ float fast_rcp(float x) {
#if __has_builtin(__builtin_amdgcn_rcpf)
  return __builtin_amdgcn_rcpf(x);
#else
  return 1.0f / x;
#endif
}
// jax.nn.gelu(approximate=True) — R5-exact formulation (absmax-16-verified)
__device__ __forceinline__ float gelu_f(float x) {
  float x3 = x * x * x;
  float u = -1.5957691216057308f * fmaf(0.044715f, x3, x);
  return x * fast_rcp(1.f + __expf(u));
}
__device__ __forceinline__ float sigm_f(float x) {
  return fast_rcp(1.f + __expf(-x));
}
__device__ __forceinline__ void splitw(float v, f16& h, f16& l) {
  h = (f16)v;
  l = (f16)(v - (float)h);
}

// ===========================================================================
__global__ __launch_bounds__(256) void k_pre(
    const float* __restrict__ node0, const float* __restrict__ W1,
    const float* __restrict__ b1, const float* __restrict__ W2a,
    const float* __restrict__ b2a, const float* __restrict__ W2b,
    const float* __restrict__ b2b, const float* __restrict__ W2c,
    const float* __restrict__ b2c, const float* __restrict__ Wx,
    const float* __restrict__ Ux, const float* __restrict__ bx,
    const float* __restrict__ bh, const float* __restrict__ W3b,
    const float* __restrict__ b3b, const float* __restrict__ W4a,
    const float* __restrict__ b4a, const float* __restrict__ W4b,
    const float* __restrict__ b4b, const float* __restrict__ W4c,
    const float* __restrict__ b4c, float* __restrict__ ws) {
  const int t = threadIdx.x;
  const int blk = blockIdx.x;
  char* wsb = (char*)ws;
  float* Qbuf = (float*)(wsb + Q_OFF);
  float* Pbuf = (float*)(wsb + P_OFF);
  char* W = wsb + WQ_OFF;

  if (blk < 256) {  // fc1a + iter-1 Q/P projection: 2 blocks/batch, 32 nodes
    __shared__ float sNode[1024];
    const int b = blk >> 1;
    const int n0 = (blk & 1) << 5;
    for (int idx = t; idx < 1024; idx += 256) {
      const int n = idx >> 5, f = idx & 31;
      float acc = b1[f];
#pragma unroll
      for (int k = 0; k < 8; ++k)
        acc = fmaf(node0[((size_t)(b * 64 + n0 + n)) * 8 + k], W1[k * 32 + f], acc);
      sNode[idx] = acc;
    }
    __syncthreads();
    for (int o = t; o < 4096; o += 256) {
      const int n = o >> 7;
      const int r = o & 127;
      const int u = r >> 1;
      const int isP = r & 1;
      const float* nr = sNode + n * 32;
      const float* wc = W2a + (isP ? 32 * 64 : 0) + u;
      float acc = isP ? 0.f : b2a[u];
#pragma unroll 8
      for (int k = 0; k < 32; ++k) acc = fmaf(nr[k], wc[k * 64], acc);
      const size_t gn = (size_t)(b * 64 + n0 + n);
      if (isP)
        Pbuf[gn * 64 + u] = acc;
      else
        Qbuf[gn * 64 + u] = acc;
    }
  } else if (blk == 256) {
    float* wb = (float*)(W + O_W45B);
    if (t < 64) {
      wb[t] = W2a[64 * 64 + t];
      wb[64 + t] = W2a[65 * 64 + t];
      wb[128 + t] = b2a[t];
    }
    f16* bth = (f16*)(W + O_W2BTH);
    f16* btl = (f16*)(W + O_W2BTL);
    for (int idx = t; idx < 2048; idx += 256) {
      const int k = idx >> 5, v = idx & 31;
      f16 h_, l_;
      splitw(W2b[k * 32 + v], h_, l_);
      bth[v * 64 + k] = h_;
      btl[v * 64 + k] = l_;
    }
    float* b2bf = (float*)(W + O_B2B);
    if (t < 32) b2bf[t] = b2b[t];
    f16* cth = (f16*)(W + O_W2CTH);
    f16* ctl = (f16*)(W + O_W2CTL);
    for (int idx = t; idx < 1024; idx += 256) {
      const int k = idx >> 5, v = idx & 31;
      f16 h_, l_;
      splitw(W2c[k * 32 + v], h_, l_);
      cth[v * 32 + k] = h_;
      ctl[v * 32 + k] = l_;
    }
    float* b2cf = (float*)(W + O_B2C);
    if (t < 32) b2cf[t] = b2c[t];
    float* lot = (float*)(W + O_W2ALOT);
    float* hit = (float*)(W + O_W2AHIT);
    for (int idx = t; idx < 2048; idx += 256) {
      const int k = idx >> 6, u = idx & 63;
      lot[u * 32 + k] = W2a[k * 64 + u];
      hit[u * 32 + k] = W2a[(k + 32) * 64 + u];
    }
  } else if (blk == 257) {
    float* wxt = (float*)(W + O_WXT);
    for (int idx = t; idx < 6144; idx += 256) {
      const int u = idx >> 5, k = idx & 31;
      wxt[u * 32 + k] = Wx[k * 192 + u];
    }
    float* bxf = (float*)(W + O_BX);
    float* bhf = (float*)(W + O_BH);
    if (t < 192) {
      bxf[t] = bx[t];
      bhf[t] = bh[t];
    }
  } else if (blk == 258) {
    float* uxt = (float*)(W + O_UXT);
    for (int idx = t; idx < 12288; idx += 256) {
      const int u = idx >> 6, k = idx & 63;
      uxt[u * 64 + k] = Ux[k * 192 + u];
    }
  } else {
    float* w3bt = (float*)(W + O_W3BT);
    for (int idx = t; idx < 2048; idx += 256) {
      const int f = idx >> 6, k = idx & 63;
      w3bt[f * 64 + k] = W3b[k * 32 + f];
    }
    float* b3bf = (float*)(W + O_B3B);
    if (t < 32) b3bf[t] = b3b[t];
    float* w4at = (float*)(W + O_W4AT);
    for (int idx = t; idx < 2048; idx += 256) {
      const int u = idx >> 5, k = idx & 31;
      w4at[u * 32 + k] = W4a[k * 64 + u];
    }
    float* b4af = (float*)(W + O_B4A);
    if (t < 64) b4af[t] = b4a[t];
    float* w4bt = (float*)(W + O_W4BT);
    for (int idx = t; idx < 2048; idx += 256) {
      const int v = idx >> 6, k = idx & 63;
      w4bt[v * 64 + k] = W4b[k * 32 + v];
    }
    float* b4bf = (float*)(W + O_B4B);
    if (t < 32) b4bf[t] = b4b[t];
    float* w4ct = (float*)(W + O_W4CT);
    for (int idx = t; idx < 1024; idx += 256) {
      const int f = idx >> 5, k = idx & 31;
      w4ct[f * 32 + k] = W4c[k * 32 + f];
    }
    float* b4cf = (float*)(W + O_B4C);
    if (t < 32) b4cf[t] = b4c[t];
  }
}

// ===========================================================================
// Edge MLP: block = (batch, 8 source nodes), wave owns 2 nodes' edge sets.
__global__ __launch_bounds__(256, 4) void k_edge(
    const float* __restrict__ edge, float* __restrict__ ws) {
  __shared__ alignas(16) char sm[LE_TOTAL];
  f16* sW2BH = (f16*)(sm + LE_W2BH);
  f16* sW2BL = (f16*)(sm + LE_W2BL);
  f16* sW2CH = (f16*)(sm + LE_W2CH);
  f16* sW2CL = (f16*)(sm + LE_W2CL);

  const int tid = threadIdx.x;
  const int lane = tid & 63;
  const int wave = tid >> 6;
  const int col = lane & 15;
  const int quad = lane >> 4;
  const int b = blockIdx.x >> 3;
  const int i0 = (blockIdx.x & 7) << 3;

  char* wsb = (char*)ws;
  float* MI = (float*)(wsb + MI_OFF);
  const float* Qbuf = (const float*)(wsb + Q_OFF);
  const float* Pbuf = (const float*)(wsb + P_OFF);
  const char* W = wsb + WQ_OFF;
  const float* w45b = (const float*)(W + O_W45B);
  const f16* W2BTHg = (const f16*)(W + O_W2BTH);
  const f16* W2BTLg = (const f16*)(W + O_W2BTL);
  const float* b2b_g = (const float*)(W + O_B2B);
  const f16* W2CTHg = (const f16*)(W + O_W2CTH);
  const f16* W2CTLg = (const f16*)(W + O_W2CTL);
  const float* b2c_g = (const float*)(W + O_B2C);

  // stage W2b/W2c hi/lo into padded LDS (bit-identical fragments to R8)
  for (int idx = tid; idx < 1024; idx += 256) {
    const int v = idx >> 5, k2 = idx & 31;
    ((unsigned int*)sW2BH)[v * 36 + k2] = ((const unsigned int*)W2BTHg)[idx];
    ((unsigned int*)sW2BL)[v * 36 + k2] = ((const unsigned int*)W2BTLg)[idx];
  }
  for (int idx = tid; idx < 512; idx += 256) {
    const int v = idx >> 4, k2 = idx & 15;
    ((unsigned int*)sW2CH)[v * 20 + k2] = ((const unsigned int*)W2CTHg)[idx];
    ((unsigned int*)sW2CL)[v * 20 + k2] = ((const unsigned int*)W2CTLg)[idx];
  }
  __syncthreads();

  const float bb2[2] = {b2b_g[col], b2b_g[16 + col]};
  const float bc2[2] = {b2c_g[col], b2c_g[16 + col]};
  f4 wav[2][2], wbv[2][2];
#pragma unroll
  for (int kh = 0; kh < 2; ++kh) {
#pragma unroll
    for (int p = 0; p < 2; ++p) {
      wav[kh][p] = *(const f4*)(w45b + kh * 32 + quad * 8 + p * 4);
      wbv[kh][p] = *(const f4*)(w45b + 64 + kh * 32 + quad * 8 + p * 4);
    }
  }
  f16* m2h = (f16*)(sm + LE_M2W + wave * 2560);
  f16* m2l = m2h + 640;

#pragma unroll 1
  for (int cc2 = 0; cc2 < 2; ++cc2) {
    const int c = wave + 4 * cc2;
    const int ig = i0 + c;
    // Q row (b2a folded), broadcast across cols: hoist to registers
    f4 qb[2][2];
#pragma unroll
    for (int kh = 0; kh < 2; ++kh)
#pragma unroll
      for (int p = 0; p < 2; ++p)
        qb[kh][p] = *(const f4*)(Qbuf + ((size_t)(b * 64 + ig)) * 64 + kh * 32 +
                                 quad * 8 + p * 4);
    const float* erow = edge + ((size_t)b * 4032 + (size_t)ig * 63) * 2;
    float ev0[4], ev1[4];
#pragma unroll
    for (int mt = 0; mt < 4; ++mt) {
      const int ko = mt * 16 + col;
      if (ko < 63) {
        const float2 e = *(const float2*)(erow + ko * 2);
        ev0[mt] = e.x;
        ev1[mt] = e.y;
      } else {
        ev0[mt] = 0.f;
        ev1[mt] = 0.f;
      }
    }
    float racc[2] = {0.f, 0.f};
#pragma unroll
    for (int mt = 0; mt < 4; ++mt) {
      const int ko = mt * 16 + col;
      int j = ko + ((ko >= ig) ? 1 : 0);
      j = (j > 63) ? 63 : j;
      const float e0 = ev0[mt], e1 = ev1[mt];
      // m1 A-fragments straight into registers (P rows from global/L2)
      h8 ah[2], al[2];
#pragma unroll
      for (int kh = 0; kh < 2; ++kh) {
        const float* prow =
            Pbuf + ((size_t)(b * 64 + j)) * 64 + kh * 32 + quad * 8;
        const f4 p0 = *(const f4*)prow;
        const f4 p1 = *(const f4*)(prow + 4);
#pragma unroll
        for (int jj = 0; jj < 4; ++jj) {
          float v = qb[kh][0][jj] + p0[jj];
          v = fmaf(e1, wbv[kh][0][jj], fmaf(e0, wav[kh][0][jj], v));
          float g = gelu_f(v) * 0.015625f;
          f16 hi = (f16)g;
          ah[kh][jj] = hi;
          al[kh][jj] = (f16)(g - (float)hi);
          v = qb[kh][1][jj] + p1[jj];
          v = fmaf(e1, wbv[kh][1][jj], fmaf(e0, wav[kh][1][jj], v));
          g = gelu_f(v) * 0.015625f;
          hi = (f16)g;
          ah[kh][4 + jj] = hi;
          al[kh][4 + jj] = (f16)(g - (float)hi);
        }
      }
      // mm2 (3-term split, K=64) — R8-exact order, B from LDS
#pragma unroll
      for (int nt = 0; nt < 2; ++nt) {
        const f16* rbh = sW2BH + (nt * 16 + col) * 72 + quad * 8;
        const f16* rbl = sW2BL + (nt * 16 + col) * 72 + quad * 8;
        const h8 bh0 = *(const h8*)rbh;
        const h8 bh1 = *(const h8*)(rbh + 32);
        const h8 bl0 = *(const h8*)rbl;
        const h8 bl1 = *(const h8*)(rbl + 32);
        f4 cm = {0.f, 0.f, 0.f, 0.f};
        cm = MFMA16(ah[0], bh0, cm);
        cm = MFMA16(ah[1], bh1, cm);
        cm = MFMA16(ah[0], bl0, cm);
        cm = MFMA16(ah[1], bl1, cm);
        cm = MFMA16(al[0], bh0, cm);
        cm = MFMA16(al[1], bh1, cm);
#pragma unroll
        for (int r = 0; r < 4; ++r) {
          const float g = gelu_f(fmaf(64.f, cm[r], bb2[nt])) * 0.015625f;
          const f16 hi = (f16)g;
          const int o = (quad * 4 + r) * 40 + nt * 16 + col;
          m2h[o] = hi;
          m2l[o] = (f16)(g - (float)hi);
        }
      }
      WFENCE();  // C-layout writes before A-layout reads (same wave)
      const h8 a2h = *(const h8*)(m2h + col * 40 + quad * 8);
      const h8 a2l = *(const h8*)(m2l + col * 40 + quad * 8);
      WFENCE();  // reads before next mt's writes (WAR)
      // mm3 (3-term split, K=32) + masked register segment-sum
#pragma unroll
      for (int nt = 0; nt < 2; ++nt) {
        const h8 bch = *(const h8*)(sW2CH + (nt * 16 + col) * 40 + quad * 8);
        const h8 bcl = *(const h8*)(sW2CL + (nt * 16 + col) * 40 + quad * 8);
        f4 dm = {0.f, 0.f, 0.f, 0.f};
        dm = MFMA16(a2h, bch, dm);
        dm = MFMA16(a2h, bcl, dm);
        dm = MFMA16(a2l, bch, dm);
#pragma unroll
        for (int r = 0; r < 4; ++r) {
          const int slot3 = mt * 16 + quad * 4 + r;
          const float g = gelu_f(fmaf(64.f, dm[r], bc2[nt]));
          racc[nt] += (slot3 != 63) ? g : 0.f;
        }
      }
    }
    // cross-quad reduction in-wave (lanes with same col), then store m_i
    racc[0] += __shfl_xor(racc[0], 16);
    racc[0] += __shfl_xor(racc[0], 32);
    racc[1] += __shfl_xor(racc[1], 16);
    racc[1] += __shfl_xor(racc[1], 32);
    if (lane < 32)
      MI[((size_t)(b * 64 + ig)) * 32 + lane] = (lane < 16) ? racc[0] : racc[1];
  }
}

// ===========================================================================
// GRU + node update + (next-iter Q/P projection | readout). 512 blocks.
// R10: all scattered weight reads routed through padded LDS stages.
__global__ __launch_bounds__(256) void k_node(
    float* __restrict__ ws, const float* __restrict__ h_in,
    float* __restrict__ out, const int is_last) {
  __shared__ alignas(16) char sm[LN_TOTAL];
  float* sH32 = (float*)(sm + LN_H32);
  float* sMI = (float*)(sm + LN_MI);
  float* sNd = (float*)(sm + LN_ND);
  float* sUx = (float*)(sm + LN_UX);
  float* sWx = (float*)(sm + LN_WX);
  float* sR = (float*)(sm + LN_R);
  float* sZ = (float*)(sm + LN_Z);
  float* sXn = (float*)(sm + LN_XN);
  float* sHng = (float*)(sm + LN_HNG);
  float* sHn32 = (float*)(sm + LN_HN32);

  const int tid = threadIdx.x;
  const int lane = tid & 63;
  const int wave = tid >> 6;
  const int b = blockIdx.x >> 2;
  const int i0 = (blockIdx.x & 3) << 4;

  char* wsb = (char*)ws;
  float* h_ws = (float*)(wsb + H_OFF);
  const float* MI = (const float*)(wsb + MI_OFF);
  float* Qbuf = (float*)(wsb + Q_OFF);
  float* Pbuf = (float*)(wsb + P_OFF);
  const char* W = wsb + WQ_OFF;
  const float* w45b = (const float*)(W + O_W45B);
  const float* WxT = (const float*)(W + O_WXT);
  const float* UxT = (const float*)(W + O_UXT);
  const float* bx_g = (const float*)(W + O_BX);
  const float* bh_g = (const float*)(W + O_BH);
  const float* W3bT = (const float*)(W + O_W3BT);
  const float* b3b_g = (const float*)(W + O_B3B);
  const float* W4aT = (const float*)(W + O_W4AT);
  const float* b4a_g = (const float*)(W + O_B4A);
  const float* W4bT = (const float*)(W + O_W4BT);
  const float* b4b_g = (const float*)(W + O_B4B);
  const float* W4cT = (const float*)(W + O_W4CT);
  const float* b4c_g = (const float*)(W + O_B4C);
  const float* W2aLOT = (const float*)(W + O_W2ALOT);
  const float* W2aHIT = (const float*)(W + O_W2AHIT);

  // stage h (coalesced) and m_i (coalesced)
  {
    const int nl = tid >> 4;
    const int k4 = (tid & 15) * 4;
    *(float4*)(sH32 + tid * 4) =
        *(const float4*)(h_in + ((size_t)(b * 64 + i0 + nl)) * 64 + k4);
  }
  if (tid < 128)
    *(float4*)(sMI + tid * 4) =
        *(const float4*)(MI + ((size_t)(b * 64 + i0)) * 32 + tid * 4);
  __syncthreads();

  // per-thread operand caches (bit-identical values to R9's global loads)
  const int n = tid >> 4;
  const int u0 = tid & 15;
  float4 mi4[8], hh4[16];
  {
    const float4* mrow = (const float4*)(sMI + n * 32);
#pragma unroll
    for (int i = 0; i < 8; ++i) mi4[i] = mrow[i];
    const float4* hrow = (const float4*)(sH32 + n * 64);
#pragma unroll
    for (int i = 0; i < 16; ++i) hh4[i] = hrow[i];
  }

  // gates in three 64-column passes; weight thirds staged to padded LDS
#pragma unroll 1
  for (int g = 0; g < 3; ++g) {
    const float* UxSrc = UxT + (size_t)(64 * g) * 64;
    for (int idx = tid; idx < 1024; idx += 256) {  // 64 rows x 16 float4
      const int r = idx >> 4, c = idx & 15;
      *(float4*)(sUx + r * 68 + c * 4) = *(const float4*)(UxSrc + r * 64 + c * 4);
    }
    const float* WxSrc = WxT + (size_t)(64 * g) * 32;
    for (int idx = tid; idx < 512; idx += 256) {   // 64 rows x 8 float4
      const int r = idx >> 3, c = idx & 7;
      *(float4*)(sWx + r * 36 + c * 4) = *(const float4*)(WxSrc + r * 32 + c * 4);
    }
    __syncthreads();
#pragma unroll
    for (int jj = 0; jj < 4; ++jj) {
      const int ul = u0 + 16 * jj;     // local gate col 0..63
      const int u = 64 * g + ul;       // global gate col
      const float4* wx = (const float4*)(sWx + ul * 36);
      float ax = 0.f;
#pragma unroll
      for (int i = 0; i < 8; ++i) {
        const float4 w = wx[i];
        ax = fmaf(mi4[i].x, w.x, ax);
        ax = fmaf(mi4[i].y, w.y, ax);
        ax = fmaf(mi4[i].z, w.z, ax);
        ax = fmaf(mi4[i].w, w.w, ax);
      }
      const float4* ux = (const float4*)(sUx + ul * 68);
      float ah_ = 0.f;
#pragma unroll
      for (int i = 0; i < 16; ++i) {
        const float4 w = ux[i];
        ah_ = fmaf(hh4[i].x, w.x, ah_);
        ah_ = fmaf(hh4[i].y, w.y, ah_);
        ah_ = fmaf(hh4[i].z, w.z, ah_);
        ah_ = fmaf(hh4[i].w, w.w, ah_);
      }
      const float bxv = bx_g[u], bhv = bh_g[u];
      if (g == 0) {
        sR[n * 64 + ul] = sigm_f(ax + ah_ + bxv + bhv);
      } else if (g == 1) {
        sZ[n * 64 + ul] = sigm_f(ax + ah_ + bxv + bhv);
      } else {
        sXn[n * 64 + ul] = ax + bxv;
        sHng[n * 64 + ul] = ah_ + bhv;
      }
    }
    __syncthreads();
  }

#pragma unroll
  for (int p = 0; p < 4; ++p) {
    const int nl = wave + 4 * p;
    const int u = lane;
    const float r_ = sR[nl * 64 + u];
    const float z_ = sZ[nl * 64 + u];
    const float n_ = gelu_f(fmaf(r_, sHng[nl * 64 + u], sXn[nl * 64 + u]));
    const float hold = sH32[nl * 64 + u];
    const float hnew = (1.f - z_) * n_ + z_ * hold;
    sHn32[nl * 64 + u] = hnew;
    h_ws[((size_t)(b * 64 + i0 + nl)) * 64 + u] = hnew;
  }
  __syncthreads();

  // node = h_new @ W3b + b3b -> sNd
  for (int t = tid; t < 512; t += 256) {
    const int nn = t >> 5, f = t & 31;
    float acc = b3b_g[f];
    const float4* hr = (const float4*)(sHn32 + nn * 64);
    const float4* wr = (const float4*)(W3bT + f * 64);
#pragma unroll
    for (int i = 0; i < 16; ++i) {
      const float4 hv = hr[i];
      const float4 wv = wr[i];
      acc = fmaf(hv.x, wv.x, acc);
      acc = fmaf(hv.y, wv.y, acc);
      acc = fmaf(hv.z, wv.z, acc);
      acc = fmaf(hv.w, wv.w, acc);
    }
    sNd[nn * 32 + f] = acc;
  }
  __syncthreads();

  if (!is_last) {
    // stage W2aLO/HI into padded LDS (gates done; stage region free)
    float* sQW = (float*)(sm + LN_QW);
    float* sPW = (float*)(sm + LN_PW);
    for (int idx = tid; idx < 512; idx += 256) {  // 64 rows x 8 float4
      const int r = idx >> 3, c = idx & 7;
      *(float4*)(sQW + r * 36 + c * 4) = *(const float4*)(W2aLOT + r * 32 + c * 4);
      *(float4*)(sPW + r * 36 + c * 4) = *(const float4*)(W2aHIT + r * 32 + c * 4);
    }
    __syncthreads();
    const int uu = tid & 15;
    const float4* nr = (const float4*)(sNd + n * 32);
    float4 nv[8];
#pragma unroll
    for (int i = 0; i < 8; ++i) nv[i] = nr[i];
    const size_t gn = (size_t)(b * 64 + i0 + n);
#pragma unroll
    for (int k8 = 0; k8 < 4; ++k8) {
      const int u = uu + (k8 << 4);
      const float4* wq = (const float4*)(sQW + u * 36);
      const float4* wp = (const float4*)(sPW + u * 36);
      float qa = w45b[128 + u];
      float pa = 0.f;
#pragma unroll
      for (int i = 0; i < 8; ++i) {
        const float4 a = nv[i];
        const float4 q = wq[i];
        const float4 p = wp[i];
        qa = fmaf(a.x, q.x, qa);
        qa = fmaf(a.y, q.y, qa);
        qa = fmaf(a.z, q.z, qa);
        qa = fmaf(a.w, q.w, qa);
        pa = fmaf(a.x, p.x, pa);
        pa = fmaf(a.y, p.y, pa);
        pa = fmaf(a.z, p.z, pa);
        pa = fmaf(a.w, p.w, pa);
      }
      Qbuf[gn * 64 + u] = qa;
      Pbuf[gn * 64 + u] = pa;
    }
  } else {
    float* sT1 = (float*)(sm + LN_T1);
    float* sT2 = (float*)(sm + LN_T2);
    for (int t = tid; t < 1024; t += 256) {
      const int nn = t >> 6, u = t & 63;
      float acc = b4a_g[u];
      const float4* ar = (const float4*)(sNd + nn * 32);
      const float4* wr = (const float4*)(W4aT + u * 32);
#pragma unroll
      for (int i = 0; i < 8; ++i) {
        const float4 av = ar[i];
        const float4 wv = wr[i];
        acc = fmaf(av.x, wv.x, acc);
        acc = fmaf(av.y, wv.y, acc);
        acc = fmaf(av.z, wv.z, acc);
        acc = fmaf(av.w, wv.w, acc);
      }
      sT1[nn * 68 + u] = acc;
    }
    __syncthreads();
    for (int t = tid; t < 512; t += 256) {
      const int nn = t >> 5, v = t & 31;
      float acc = b4b_g[v];
      const float4* ar = (const float4*)(sT1 + nn * 68);
      const float4* wr = (const float4*)(W4bT + v * 64);
#pragma unroll
      for (int i = 0; i < 16; ++i) {
        const float4 av = ar[i];
        const float4 wv = wr[i];
        acc = fmaf(av.x, wv.x, acc);
        acc = fmaf(av.y, wv.y, acc);
        acc = fmaf(av.z, wv.z, acc);
        acc = fmaf(av.w, wv.w, acc);
      }
      sT2[nn * 36 + v] = acc;
    }
    __syncthreads();
    for (int t = tid; t < 512; t += 256) {
      const int nn = t >> 5, f = t & 31;
      float acc = b4c_g[f];
      const float4* ar = (const float4*)(sT2 + nn * 36);
      const float4* wr = (const float4*)(W4cT + f * 32);
#pragma unroll
      for (int i = 0; i < 8; ++i) {
        const float4 av = ar[i];
        const float4 wv = wr[i];
        acc = fmaf(av.x, wv.x, acc);
        acc = fmaf(av.y, wv.y, acc);
        acc = fmaf(av.z, wv.z, acc);
        acc = fmaf(av.w, wv.w, acc);
      }
      out[((size_t)(b * 64 + i0 + nn)) * 32 + f] = acc;
    }
  }
}

// ===========================================================================
extern "C" void kernel_launch(void* const* d_in, const int* in_sizes, int n_in,
                              void* d_out, int out_size, void* d_ws, size_t ws_size,
                              hipStream_t stream) {
  (void)in_sizes;
  (void)n_in;
  (void)out_size;
  (void)ws_size;
  const float* node0 = (const float*)d_in[0];
  const float* edge = (const float*)d_in[1];
  const float* hin = (const float*)d_in[4];
  const float* W1 = (const float*)d_in[5];
  const float* b1 = (const float*)d_in[6];
  const float* W2a = (const float*)d_in[7];
  const float* b2a = (const float*)d_in[8];
  const float* W2b = (const float*)d_in[9];
  const float* b2b = (const float*)d_in[10];
  const float* W2c = (const float*)d_in[11];
  const float* b2c = (const float*)d_in[12];
  const float* Wx = (const float*)d_in[13];
  const float* Ux = (const float*)d_in[14];
  const float* bx = (const float*)d_in[15];
  const float* bh = (const float*)d_in[16];
  const float* W3b = (const float*)d_in[17];
  const float* b3b = (const float*)d_in[18];
  const float* W4a = (const float*)d_in[19];
  const float* b4a = (const float*)d_in[20];
  const float* W4b = (const float*)d_in[21];
  const float* b4b = (const float*)d_in[22];
  const float* W4c = (const float*)d_in[23];
  const float* b4c = (const float*)d_in[24];

  float* ws = (float*)d_ws;
  char* wsb = (char*)d_ws;
  float* h_ws = (float*)(wsb + H_OFF);
  float* out = (float*)d_out;

  k_pre<<<dim3(260), dim3(256), 0, stream>>>(node0, W1, b1, W2a, b2a, W2b, b2b, W2c,
                                             b2c, Wx, Ux, bx, bh, W3b, b3b, W4a, b4a,
                                             W4b, b4b, W4c, b4c, ws);
  k_edge<<<dim3(1024), dim3(256), 0, stream>>>(edge, ws);
  k_node<<<dim3(512), dim3(256), 0, stream>>>(ws, hin, nullptr, 0);
  k_edge<<<dim3(1024), dim3(256), 0, stream>>>(edge, ws);
  k_node<<<dim3(512), dim3(256), 0, stream>>>(ws, h_ws, nullptr, 0);
  k_edge<<<dim3(1024), dim3(256), 0, stream>>>(edge, ws);
  k_node<<<dim3(512), dim3(256), 0, stream>>>(ws, h_ws, out, 1);
}